// Round 20
// baseline (238.665 us; speedup 1.0000x reference)
//
#include <hip/hip_runtime.h>
#include <math.h>

#define B_ 16
#define N_ 16384
#define C_ 256
#define H_ 128
#define K_ 11468   // int(16384 * 0.7)
#define G_ ((B_ * N_) / 16)   // 16384 groups of 16 tokens
#define GPB_ 16               // groups per block
#define NBLK_ (G_ / GPB_)     // 1024 blocks

typedef __attribute__((ext_vector_type(8))) short s16x8;
typedef __attribute__((ext_vector_type(4))) float f32x4;
typedef __attribute__((ext_vector_type(4))) unsigned int u32x4;

__device__ __forceinline__ unsigned short f2bf(float f) {
  unsigned u = __builtin_bit_cast(unsigned, f);
  return (unsigned short)((u + 0x7FFFu + ((u >> 16) & 1u)) >> 16);  // RNE
}
// order-preserving map fp32 -> uint32 (no NaNs expected)
__device__ __forceinline__ unsigned fkey(float f) {
  unsigned u = __builtin_bit_cast(unsigned, f);
  return (u & 0x80000000u) ? ~u : (u | 0x80000000u);
}
// pack two fp32 to two bf16 (truncation) in one v_perm — same bits as rounds 4-19
__device__ __forceinline__ unsigned pk2(float hi, float lo) {
  return __builtin_amdgcn_perm(__builtin_bit_cast(unsigned, hi),
                               __builtin_bit_cast(unsigned, lo), 0x07060302u);
}

#define LDS_BARRIER()                                     \
  do {                                                    \
    asm volatile("s_waitcnt lgkmcnt(0)" ::: "memory");    \
    __builtin_amdgcn_s_barrier();                         \
  } while (0)

__device__ __forceinline__ float gelu_fast(float h) {
  const float t = 0.5f * h * h;
  const float u = 0.147f * t;
  const float num = t * (1.2732395f + u);
  const float den = 1.0f + u;
  const float r = num * __builtin_amdgcn_rcpf(den);
  const float e = __builtin_amdgcn_exp2f(r * -1.44269504f);
  const float s = __builtin_amdgcn_sqrtf(fmaxf(1.0f - e, 0.0f));
  const unsigned sgn = __builtin_bit_cast(unsigned, h) & 0x80000000u;
  const float erfv = __builtin_bit_cast(float, __builtin_bit_cast(unsigned, s) | sgn);
  return 0.5f * h * (1.0f + erfv);
}

// ---- w1 fp32 [C][H] -> plain bf16 transpose w1t[H][C] ----
__global__ void k_prep(const float* __restrict__ w1, unsigned short* __restrict__ w1t) {
  int i = blockIdx.x * blockDim.x + threadIdx.x;
  if (i < C_ * H_) {
    int c = i / H_, h = i % H_;
    w1t[h * C_ + c] = f2bf(w1[i]);
  }
}

// ---------------- fused scorer (round-16 structure, unchanged) ----------------
__global__ __launch_bounds__(256) void k_score(
    const float* __restrict__ tokens, const unsigned short* __restrict__ w1t,
    const float* __restrict__ b1, const float* __restrict__ w2,
    const float* __restrict__ b2, float* __restrict__ scores_out) {
  __shared__ unsigned short lds_a[2][8 * 64 * 8];
  __shared__ float lds_c[4][16];

  const int tid = threadIdx.x;
  const int lane = tid & 63;
  const int l15 = lane & 15;
  const int l4 = lane >> 4;
  const int w = tid >> 6;

  s16x8 bfr0[8], bfr1[8];
  const int row0 = (2 * w) * 16 + l15;
  const int row1 = row0 + 16;
#pragma unroll
  for (int kk = 0; kk < 8; ++kk) {
    bfr0[kk] = *reinterpret_cast<const s16x8*>(w1t + row0 * 256 + (l4 + 4 * kk) * 8);
    bfr1[kk] = *reinterpret_cast<const s16x8*>(w1t + row1 * 256 + (l4 + 4 * kk) * 8);
  }
  const float b1v0 = b1[row0], b1v1 = b1[row1];
  const float w2v0 = w2[row0], w2v1 = w2[row1];
  const float b2v = b2[0];

  const int t = tid & 15;
  const int s = tid >> 4;
  const int g0 = blockIdx.x * GPB_;
  const float* tg = tokens + ((size_t)(g0 * 16 + t)) * 256 + s * 16;
  const int lb0 = (2 * s) * 128 + t * 8;
  const int lb1 = lb0 + 128;

  f32x4 vv[4];
  {
#pragma unroll
    for (int q = 0; q < 4; ++q) vv[q] = *reinterpret_cast<const f32x4*>(tg + 4 * q);
    u32x4 o0, o1;
    o0[0] = pk2(vv[0][1], vv[0][0]);
    o0[1] = pk2(vv[0][3], vv[0][2]);
    o0[2] = pk2(vv[1][1], vv[1][0]);
    o0[3] = pk2(vv[1][3], vv[1][2]);
    o1[0] = pk2(vv[2][1], vv[2][0]);
    o1[1] = pk2(vv[2][3], vv[2][2]);
    o1[2] = pk2(vv[3][1], vv[3][0]);
    o1[3] = pk2(vv[3][3], vv[3][2]);
    *reinterpret_cast<u32x4*>(&lds_a[0][lb0]) = o0;
    *reinterpret_cast<u32x4*>(&lds_a[0][lb1]) = o1;
  }
  LDS_BARRIER();

  int cur = 0;
  for (int i = 0; i < GPB_; ++i) {
    const int g = g0 + i;
    if (i + 1 < GPB_) {
      const float* p = tg + (size_t)(i + 1) * 4096;
#pragma unroll
      for (int q = 0; q < 4; ++q) vv[q] = *reinterpret_cast<const f32x4*>(p + 4 * q);
    }

    f32x4 acc0 = (f32x4){0.f, 0.f, 0.f, 0.f};
    f32x4 acc1 = (f32x4){0.f, 0.f, 0.f, 0.f};
#pragma unroll
    for (int kk = 0; kk < 8; ++kk) {
      s16x8 a = *reinterpret_cast<const s16x8*>(&lds_a[cur][(kk * 64 + lane) * 8]);
      acc0 = __builtin_amdgcn_mfma_f32_16x16x32_bf16(a, bfr0[kk], acc0, 0, 0, 0);
      acc1 = __builtin_amdgcn_mfma_f32_16x16x32_bf16(a, bfr1[kk], acc1, 0, 0, 0);
    }

    float p4[4];
#pragma unroll
    for (int rr = 0; rr < 4; ++rr) {
      float sp = gelu_fast(acc0[rr] + b1v0) * w2v0 + gelu_fast(acc1[rr] + b1v1) * w2v1;
      sp += __shfl_xor(sp, 1);
      sp += __shfl_xor(sp, 2);
      sp += __shfl_xor(sp, 4);
      sp += __shfl_xor(sp, 8);
      p4[rr] = sp;
    }
    if (l15 == 0) {
#pragma unroll
      for (int rr = 0; rr < 4; ++rr) lds_c[w][l4 * 4 + rr] = p4[rr];
    }
    LDS_BARRIER();  // (A)

    if (tid < 16) {
      scores_out[g * 16 + tid] =
          lds_c[0][tid] + lds_c[1][tid] + lds_c[2][tid] + lds_c[3][tid] + b2v;
    }
    if (i + 1 < GPB_) {
      u32x4 o0, o1;
      o0[0] = pk2(vv[0][1], vv[0][0]);
      o0[1] = pk2(vv[0][3], vv[0][2]);
      o0[2] = pk2(vv[1][1], vv[1][0]);
      o0[3] = pk2(vv[1][3], vv[1][2]);
      o1[0] = pk2(vv[2][1], vv[2][0]);
      o1[1] = pk2(vv[2][3], vv[2][2]);
      o1[2] = pk2(vv[3][1], vv[3][0]);
      o1[3] = pk2(vv[3][3], vv[3][2]);
      *reinterpret_cast<u32x4*>(&lds_a[cur ^ 1][lb0]) = o0;
      *reinterpret_cast<u32x4*>(&lds_a[cur ^ 1][lb1]) = o1;
    }
    LDS_BARRIER();  // (B)
    cur ^= 1;
  }
}

// ---- block exscan over 1024 threads; wave-parallel cross-wave scan ----
__device__ unsigned block_exscan_1024(unsigned v, volatile unsigned* wsum) {
  const int tid = threadIdx.x;
  const int lane = tid & 63;
  const int w = tid >> 6;  // 0..15
  unsigned x = v;
#pragma unroll
  for (int d = 1; d < 64; d <<= 1) {
    unsigned t = __shfl_up(x, d);
    if (lane >= d) x += t;
  }
  if (lane == 63) wsum[w] = x;
  __syncthreads();
  if (tid < 16) {
    unsigned s = wsum[tid];
#pragma unroll
    for (int d = 1; d < 16; d <<= 1) {
      unsigned u = __shfl_up(s, d);
      if (tid >= d) s += u;
    }
    wsum[tid] = s;  // inclusive wave sums
  }
  __syncthreads();
  unsigned r = (w ? wsum[w - 1] : 0u) + x - v;  // exclusive
  __syncthreads();  // protect wsum for the next call
  return r;
}

// ---------------- per-row top-K: 1 hist pass + candidate-rank + 1 write pass ----------------
// Threshold bin T0 (11-bit) holds ~Poisson(N/2048=8) elements; instead of two more
// radix passes, collect them and rank by (key desc, idx asc) directly.
__global__ __launch_bounds__(1024) void k_select(const float* __restrict__ scores_f,
                                                 int* __restrict__ kept,
                                                 float* __restrict__ out_idx) {
  __shared__ unsigned hist[2048];   // 8 KB; reused as (key,idx) candidate pairs
  __shared__ unsigned wsum[16];
  __shared__ unsigned sh_T, sh_need, sh_m;
  const int b = blockIdx.x;
  const int tid = threadIdx.x;
  const float* sp = scores_f + (size_t)b * N_;

  // ---- scan 1: 11-bit histogram (2048 bins)
  hist[tid] = 0; hist[tid + 1024] = 0;
  __syncthreads();
  for (int i = tid; i < N_; i += 1024) atomicAdd(&hist[fkey(sp[i]) >> 21], 1u);
  __syncthreads();
  {
    const int hi = 2047 - 2 * tid, lo = hi - 1;
    const unsigned chi = hist[hi], pair = chi + hist[lo];
    unsigned before = block_exscan_1024(pair, wsum);  // keys in bins > hi
    if (before < K_ && before + chi >= K_) { sh_T = (unsigned)hi; sh_need = K_ - before; }
    else if (before + chi < K_ && before + pair >= K_) { sh_T = (unsigned)lo; sh_need = K_ - before - chi; }
    if (tid == 0) sh_m = 0;
  }
  __syncthreads();
  const unsigned T0 = sh_T;      // threshold bin
  const unsigned need = sh_need; // # to keep from bin T0 (by key desc, idx asc)
  __syncthreads();               // hist reads done -> safe to reuse as cand

  // ---- scan 2: count bin>T0 per thread; collect bin==T0 candidates
  unsigned* cand = hist;         // pairs: cand[2e]=key, cand[2e+1]=idx (bit31=selected)
  const int i0 = tid * 16;
  unsigned cgt = 0;
  for (int j = 0; j < 16; ++j) {
    unsigned k = fkey(sp[i0 + j]);
    unsigned bin = k >> 21;
    cgt += (bin > T0);
    if (bin == T0) {
      unsigned e = atomicAdd(&sh_m, 1u);
      if (e < 1024u) { cand[2 * e] = k; cand[2 * e + 1] = (unsigned)(i0 + j); }
    }
  }
  unsigned gt_base = block_exscan_1024(cgt, wsum);  // internal barriers publish cand
  const unsigned m = (sh_m < 1024u) ? sh_m : 1024u;

  // ---- rank candidates: keep rank < need by (key desc, idx asc); flag bit31 of idx
  for (unsigned e = tid; e < m; e += 1024) {
    const unsigned ke = cand[2 * e];
    const unsigned ie = cand[2 * e + 1] & 0x7FFFFFFFu;
    unsigned r = 0;
    for (unsigned f = 0; f < m; ++f) {
      const unsigned kf = cand[2 * f];
      const unsigned fi = cand[2 * f + 1] & 0x7FFFFFFFu;  // mask flag: race-free
      r += (kf > ke) || (kf == ke && fi < ie);
    }
    if (r < need) cand[2 * e + 1] |= 0x80000000u;
  }
  __syncthreads();

  // ---- scan 3: write output in index order
  unsigned gt_run = gt_base;
  for (int j = 0; j < 16; ++j) {
    const unsigned i = (unsigned)(i0 + j);
    const unsigned k = fkey(sp[i0 + j]);
    const unsigned bin = k >> 21;
    if (bin > T0) {
      unsigned eqb = 0;
      for (unsigned f = 0; f < m; ++f) {
        const unsigned fi = cand[2 * f + 1];
        eqb += (fi >> 31) & ((fi & 0x7FFFFFFFu) < i);
      }
      const unsigned pos = gt_run + eqb;
      kept[(size_t)b * K_ + pos] = (int)i;
      out_idx[(size_t)b * K_ + pos] = (float)i;
      ++gt_run;
    } else if (bin == T0) {
      unsigned eqb = 0, sel = 0;
      for (unsigned f = 0; f < m; ++f) {
        const unsigned fi = cand[2 * f + 1];
        const unsigned fidx = fi & 0x7FFFFFFFu;
        const unsigned flg = fi >> 31;
        eqb += flg & (fidx < i);
        sel |= flg & (fidx == i);
      }
      if (sel) {
        const unsigned pos = gt_run + eqb;
        kept[(size_t)b * K_ + pos] = (int)i;
        out_idx[(size_t)b * K_ + pos] = (float)i;
      }
    }
  }
}

// ---------------- gather kept token rows (fp32 -> fp32) ----------------
__global__ __launch_bounds__(256) void k_gather(const float* __restrict__ tokens,
                                                const int* __restrict__ kept,
                                                float* __restrict__ outp) {
  const int wid = (blockIdx.x * blockDim.x + threadIdx.x) >> 6;  // one wave per row
  const int lane = threadIdx.x & 63;
  if (wid >= B_ * K_) return;
  const int b = wid / K_;
  const int idx = kept[wid];
  const f32x4 v = *reinterpret_cast<const f32x4*>(tokens + ((size_t)b * N_ + idx) * C_ + lane * 4);
  *reinterpret_cast<f32x4*>(outp + (size_t)wid * C_ + lane * 4) = v;
}

extern "C" void kernel_launch(void* const* d_in, const int* in_sizes, int n_in,
                              void* d_out, int out_size, void* d_ws, size_t ws_size,
                              hipStream_t stream) {
  const float* tokens = (const float*)d_in[0];
  const float* w1 = (const float*)d_in[1];
  const float* b1 = (const float*)d_in[2];
  const float* w2 = (const float*)d_in[3];
  const float* b2 = (const float*)d_in[4];

  float* out = (float*)d_out;
  float* out_pruned = out;                                  // B*K*C fp32
  float* out_idx = out + (size_t)B_ * K_ * C_;              // B*K fp32
  float* out_scores = out_idx + (size_t)B_ * K_;            // B*N fp32

  char* ws = (char*)d_ws;
  unsigned short* w1t = (unsigned short*)ws;                // 64 KB plain bf16 W1^T
  int* kept = (int*)(ws + 0x10000);                         // B*K int32

  k_prep<<<dim3((C_ * H_ + 255) / 256), dim3(256), 0, stream>>>(w1, w1t);
  k_score<<<dim3(NBLK_), dim3(256), 0, stream>>>(tokens, w1t, b1, w2, b2, out_scores);
  k_select<<<dim3(B_), dim3(1024), 0, stream>>>(out_scores, kept, out_idx);
  k_gather<<<dim3((B_ * K_ + 3) / 4), dim3(256), 0, stream>>>(tokens, kept, out_pruned);
}

// Round 21
// 161.295 us; speedup vs baseline: 1.4797x; 1.4797x over previous
//
#include <hip/hip_runtime.h>
#include <math.h>

#define B_ 16
#define N_ 16384
#define C_ 256
#define H_ 128
#define K_ 11468   // int(16384 * 0.7)
#define G_ ((B_ * N_) / 16)   // 16384 groups of 16 tokens
#define GPB_ 16               // groups per block
#define NBLK_ (G_ / GPB_)     // 1024 blocks

typedef __attribute__((ext_vector_type(8))) short s16x8;
typedef __attribute__((ext_vector_type(4))) float f32x4;
typedef __attribute__((ext_vector_type(4))) unsigned int u32x4;

__device__ __forceinline__ unsigned short f2bf(float f) {
  unsigned u = __builtin_bit_cast(unsigned, f);
  return (unsigned short)((u + 0x7FFFu + ((u >> 16) & 1u)) >> 16);  // RNE
}
// order-preserving map fp32 -> uint32 (no NaNs expected)
__device__ __forceinline__ unsigned fkey(float f) {
  unsigned u = __builtin_bit_cast(unsigned, f);
  return (u & 0x80000000u) ? ~u : (u | 0x80000000u);
}
// pack two fp32 to two bf16 (truncation) in one v_perm — same bits as rounds 4-20
__device__ __forceinline__ unsigned pk2(float hi, float lo) {
  return __builtin_amdgcn_perm(__builtin_bit_cast(unsigned, hi),
                               __builtin_bit_cast(unsigned, lo), 0x07060302u);
}

#define LDS_BARRIER()                                     \
  do {                                                    \
    asm volatile("s_waitcnt lgkmcnt(0)" ::: "memory");    \
    __builtin_amdgcn_s_barrier();                         \
  } while (0)

// async 16B global->LDS DMA (no VGPR round-trip); LDS dest = wave base + lane*16
__device__ __forceinline__ void async_copy16(const float* g, float* l) {
  __builtin_amdgcn_global_load_lds(
      (const __attribute__((address_space(1))) unsigned int*)g,
      (__attribute__((address_space(3))) unsigned int*)l, 16, 0, 0);
}

__device__ __forceinline__ float gelu_fast(float h) {
  const float t = 0.5f * h * h;
  const float u = 0.147f * t;
  const float num = t * (1.2732395f + u);
  const float den = 1.0f + u;
  const float r = num * __builtin_amdgcn_rcpf(den);
  const float e = __builtin_amdgcn_exp2f(r * -1.44269504f);
  const float s = __builtin_amdgcn_sqrtf(fmaxf(1.0f - e, 0.0f));
  const unsigned sgn = __builtin_bit_cast(unsigned, h) & 0x80000000u;
  const float erfv = __builtin_bit_cast(float, __builtin_bit_cast(unsigned, s) | sgn);
  return 0.5f * h * (1.0f + erfv);
}

// ---- w1 fp32 [C][H] -> plain bf16 transpose w1t[H][C] ----
__global__ void k_prep(const float* __restrict__ w1, unsigned short* __restrict__ w1t) {
  int i = blockIdx.x * blockDim.x + threadIdx.x;
  if (i < C_ * H_) {
    int c = i / H_, h = i % H_;
    w1t[h * C_ + c] = f2bf(w1[i]);
  }
}

// ---------------- fused scorer: global_load_lds fp32 staging, read-side pack ----------------
// LDS slot s (16B) holds global chunk (t = s&15, c = s>>4) of the group (column-
// major): read-side ds_read_b128 gets slot%8 == l15%8 -> conflict-free cohorts,
// and the staging wave's per-lane GLOBAL address realizes the permutation while
// the LDS dest stays linear (base + lane*16), as global_load_lds requires.
// fp32 staged raw; fp32->bf16 pack moved to read side (same pk2 pairs -> scores
// bit-identical to rounds 13-20).
__global__ __launch_bounds__(256) void k_score(
    const float* __restrict__ tokens, const unsigned short* __restrict__ w1t,
    const float* __restrict__ b1, const float* __restrict__ w2,
    const float* __restrict__ b2, float* __restrict__ scores_out) {
  __shared__ float lds_f[2][4096];   // 2 x 16KB raw fp32 group buffers
  __shared__ float lds_c[4][16];     // per-wave partial scores

  const int tid = threadIdx.x;
  const int lane = tid & 63;
  const int l15 = lane & 15;
  const int l4 = lane >> 4;
  const int w = tid >> 6;

  // W1 fragments for this wave's hidden blocks nb=2w (row0) and nb=2w+1 (row1)
  s16x8 bfr0[8], bfr1[8];
  const int row0 = (2 * w) * 16 + l15;
  const int row1 = row0 + 16;
#pragma unroll
  for (int kk = 0; kk < 8; ++kk) {
    bfr0[kk] = *reinterpret_cast<const s16x8*>(w1t + row0 * 256 + (l4 + 4 * kk) * 8);
    bfr1[kk] = *reinterpret_cast<const s16x8*>(w1t + row1 * 256 + (l4 + 4 * kk) * 8);
  }
  const float b1v0 = b1[row0], b1v1 = b1[row1];
  const float w2v0 = w2[row0], w2v1 = w2[row1];
  const float b2v = b2[0];

  const int g0 = blockIdx.x * GPB_;
  const float* gbase = tokens + (size_t)g0 * 16 * 256;  // +i*4096 floats per group

  // this lane's 4 staging slots (wave w, rounds r=0..3): s = (w*4+r)*64 + lane
  int st_[4], sc_[4];
#pragma unroll
  for (int r = 0; r < 4; ++r) {
    const int sslot = (w * 4 + r) * 64 + lane;
    st_[r] = sslot & 15;   // token
    sc_[r] = sslot >> 4;   // 16B chunk within token
  }

  // read-side base slot: fragment kk reads slots sbase+128kk and sbase+128kk+16
  const int sbase = 32 * l4 + l15;

  // prologue: stage group 0 -> buffer 0
#pragma unroll
  for (int r = 0; r < 4; ++r) {
    async_copy16(gbase + st_[r] * 256 + sc_[r] * 4,
                 &lds_f[0][(size_t)((w * 4 + r) * 64 + lane) * 4]);
  }
  __syncthreads();

  int cur = 0;
  for (int i = 0; i < GPB_; ++i) {
    const int g = g0 + i;
    // (1) async-stage group i+1 into the other buffer (free since last barrier B)
    if (i + 1 < GPB_) {
      const float* gp = gbase + (size_t)(i + 1) * 4096;
#pragma unroll
      for (int r = 0; r < 4; ++r) {
        async_copy16(gp + st_[r] * 256 + sc_[r] * 4,
                     &lds_f[cur ^ 1][(size_t)((w * 4 + r) * 64 + lane) * 4]);
      }
    }

    // (2) MFMA: read fp32 from LDS, pack inline, 16 MFMAs
    const f32x4* bufp = reinterpret_cast<const f32x4*>(&lds_f[cur][0]);
    f32x4 acc0 = (f32x4){0.f, 0.f, 0.f, 0.f};
    f32x4 acc1 = (f32x4){0.f, 0.f, 0.f, 0.f};
#pragma unroll
    for (int kk = 0; kk < 8; ++kk) {
      const f32x4 va = bufp[sbase + 128 * kk];
      const f32x4 vb = bufp[sbase + 128 * kk + 16];
      u32x4 o;
      o[0] = pk2(va[1], va[0]);
      o[1] = pk2(va[3], va[2]);
      o[2] = pk2(vb[1], vb[0]);
      o[3] = pk2(vb[3], vb[2]);
      const s16x8 a = __builtin_bit_cast(s16x8, o);
      acc0 = __builtin_amdgcn_mfma_f32_16x16x32_bf16(a, bfr0[kk], acc0, 0, 0, 0);
      acc1 = __builtin_amdgcn_mfma_f32_16x16x32_bf16(a, bfr1[kk], acc1, 0, 0, 0);
    }

    // (3) partial epilogue; reduce over l15
    float p4[4];
#pragma unroll
    for (int rr = 0; rr < 4; ++rr) {
      float sp = gelu_fast(acc0[rr] + b1v0) * w2v0 + gelu_fast(acc1[rr] + b1v1) * w2v1;
      sp += __shfl_xor(sp, 1);
      sp += __shfl_xor(sp, 2);
      sp += __shfl_xor(sp, 4);
      sp += __shfl_xor(sp, 8);
      p4[rr] = sp;
    }
    if (l15 == 0) {
#pragma unroll
      for (int rr = 0; rr < 4; ++rr) lds_c[w][l4 * 4 + rr] = p4[rr];
    }
    LDS_BARRIER();  // (A) lds_c visible; lds_f[cur] reads complete

    if (tid < 16) {
      scores_out[g * 16 + tid] =
          lds_c[0][tid] + lds_c[1][tid] + lds_c[2][tid] + lds_c[3][tid] + b2v;
    }
    __syncthreads();  // (B) drains DMA (full iteration of cover) + lds_c consumed
    cur ^= 1;
  }
}

// ---- block exscan over 1024 threads; wave-parallel cross-wave scan ----
__device__ unsigned block_exscan_1024(unsigned v, volatile unsigned* wsum) {
  const int tid = threadIdx.x;
  const int lane = tid & 63;
  const int w = tid >> 6;  // 0..15
  unsigned x = v;
#pragma unroll
  for (int d = 1; d < 64; d <<= 1) {
    unsigned t = __shfl_up(x, d);
    if (lane >= d) x += t;
  }
  if (lane == 63) wsum[w] = x;
  __syncthreads();
  if (tid < 16) {
    unsigned s = wsum[tid];
#pragma unroll
    for (int d = 1; d < 16; d <<= 1) {
      unsigned u = __shfl_up(s, d);
      if (tid >= d) s += u;
    }
    wsum[tid] = s;  // inclusive wave sums
  }
  __syncthreads();
  unsigned r = (w ? wsum[w - 1] : 0u) + x - v;  // exclusive
  __syncthreads();  // protect wsum for the next call
  return r;
}

// ---------------- per-row top-K: 3-pass radix (11/11/10) + fused compaction ----------------
__global__ __launch_bounds__(1024) void k_select(const float* __restrict__ scores_f,
                                                 int* __restrict__ kept,
                                                 float* __restrict__ out_idx) {
  __shared__ unsigned hist[2048];   // 8 KB
  __shared__ unsigned wsum[16];
  __shared__ unsigned sh_T, sh_need;
  const int b = blockIdx.x;
  const int tid = threadIdx.x;
  const float* sp = scores_f + (size_t)b * N_;

  // ---- pass 0: bits [31:21] (11 bits, 2048 bins)
  hist[tid] = 0; hist[tid + 1024] = 0;
  __syncthreads();
  for (int i = tid; i < N_; i += 1024) atomicAdd(&hist[fkey(sp[i]) >> 21], 1u);
  __syncthreads();
  {
    const int hi = 2047 - 2 * tid, lo = hi - 1;
    const unsigned chi = hist[hi], pair = chi + hist[lo];
    unsigned before = block_exscan_1024(pair, wsum);  // keys in bins > hi
    if (before < K_ && before + chi >= K_) { sh_T = (unsigned)hi; sh_need = K_ - before; }
    else if (before + chi < K_ && before + pair >= K_) { sh_T = (unsigned)lo; sh_need = K_ - before - chi; }
  }
  __syncthreads();
  const unsigned T0 = sh_T;
  unsigned needK = sh_need;
  __syncthreads();

  // ---- pass 1: bits [20:10] among keys with top11 == T0
  hist[tid] = 0; hist[tid + 1024] = 0;
  __syncthreads();
  for (int i = tid; i < N_; i += 1024) {
    unsigned k = fkey(sp[i]);
    if ((k >> 21) == T0) atomicAdd(&hist[(k >> 10) & 2047u], 1u);
  }
  __syncthreads();
  {
    const int hi = 2047 - 2 * tid, lo = hi - 1;
    const unsigned chi = hist[hi], pair = chi + hist[lo];
    unsigned before = block_exscan_1024(pair, wsum);
    if (before < needK && before + chi >= needK) { sh_T = (unsigned)hi; sh_need = needK - before; }
    else if (before + chi < needK && before + pair >= needK) { sh_T = (unsigned)lo; sh_need = needK - before - chi; }
  }
  __syncthreads();
  const unsigned P21 = (T0 << 11) | sh_T;   // 21-bit prefix
  needK = sh_need;
  __syncthreads();

  // ---- pass 2: bits [9:0] among keys with top21 == P21 (1024 bins, 1/thread)
  hist[tid] = 0;
  __syncthreads();
  for (int i = tid; i < N_; i += 1024) {
    unsigned k = fkey(sp[i]);
    if ((k >> 10) == P21) atomicAdd(&hist[k & 1023u], 1u);
  }
  __syncthreads();
  {
    const int hi = 1023 - tid;
    const unsigned chi = hist[hi];
    unsigned before = block_exscan_1024(chi, wsum);
    if (before < needK && before + chi >= needK) { sh_T = (unsigned)hi; sh_need = needK - before; }
  }
  __syncthreads();
  const unsigned Tkey = (P21 << 10) | sh_T;   // exact K-th largest key
  const unsigned need = sh_need;              // #(==Tkey) kept, lowest index first
  __syncthreads();

  // ---- fused stable compaction: one packed exscan
  const int i0 = tid * 16;
  unsigned cgt = 0, ceq = 0;
  for (int j = 0; j < 16; ++j) {
    unsigned k = fkey(sp[i0 + j]);
    cgt += (k > Tkey);
    ceq += (k == Tkey);
  }
  unsigned packed = block_exscan_1024((cgt << 16) | ceq, wsum);
  unsigned gt_b = packed >> 16;
  unsigned eq_b = packed & 0xFFFFu;
  for (int j = 0; j < 16; ++j) {
    unsigned k = fkey(sp[i0 + j]);
    if (k > Tkey) {
      unsigned pos = gt_b + (eq_b < need ? eq_b : need);
      kept[(size_t)b * K_ + pos] = i0 + j;
      out_idx[(size_t)b * K_ + pos] = (float)(i0 + j);
      ++gt_b;
    } else if (k == Tkey) {
      if (eq_b < need) {
        unsigned pos = gt_b + eq_b;
        kept[(size_t)b * K_ + pos] = i0 + j;
        out_idx[(size_t)b * K_ + pos] = (float)(i0 + j);
      }
      ++eq_b;
    }
  }
}

// ---------------- gather kept token rows (fp32 -> fp32) ----------------
__global__ __launch_bounds__(256) void k_gather(const float* __restrict__ tokens,
                                                const int* __restrict__ kept,
                                                float* __restrict__ outp) {
  const int wid = (blockIdx.x * blockDim.x + threadIdx.x) >> 6;  // one wave per row
  const int lane = threadIdx.x & 63;
  if (wid >= B_ * K_) return;
  const int b = wid / K_;
  const int idx = kept[wid];
  const f32x4 v = *reinterpret_cast<const f32x4*>(tokens + ((size_t)b * N_ + idx) * C_ + lane * 4);
  *reinterpret_cast<f32x4*>(outp + (size_t)wid * C_ + lane * 4) = v;
}

extern "C" void kernel_launch(void* const* d_in, const int* in_sizes, int n_in,
                              void* d_out, int out_size, void* d_ws, size_t ws_size,
                              hipStream_t stream) {
  const float* tokens = (const float*)d_in[0];
  const float* w1 = (const float*)d_in[1];
  const float* b1 = (const float*)d_in[2];
  const float* w2 = (const float*)d_in[3];
  const float* b2 = (const float*)d_in[4];

  float* out = (float*)d_out;
  float* out_pruned = out;                                  // B*K*C fp32
  float* out_idx = out + (size_t)B_ * K_ * C_;              // B*K fp32
  float* out_scores = out_idx + (size_t)B_ * K_;            // B*N fp32

  char* ws = (char*)d_ws;
  unsigned short* w1t = (unsigned short*)ws;                // 64 KB plain bf16 W1^T
  int* kept = (int*)(ws + 0x10000);                         // B*K int32

  k_prep<<<dim3((C_ * H_ + 255) / 256), dim3(256), 0, stream>>>(w1, w1t);
  k_score<<<dim3(NBLK_), dim3(256), 0, stream>>>(tokens, w1t, b1, w2, b2, out_scores);
  k_select<<<dim3(B_), dim3(1024), 0, stream>>>(out_scores, kept, out_idx);
  k_gather<<<dim3((B_ * K_ + 3) / 4), dim3(256), 0, stream>>>(tokens, kept, out_pruned);
}

// Round 22
// 159.479 us; speedup vs baseline: 1.4965x; 1.0114x over previous
//
#include <hip/hip_runtime.h>
#include <math.h>

#define B_ 16
#define N_ 16384
#define C_ 256
#define H_ 128
#define K_ 11468   // int(16384 * 0.7)
#define G_ ((B_ * N_) / 16)   // 16384 groups of 16 tokens
#define GPB_ 16               // groups per block
#define NBLK_ (G_ / GPB_)     // 1024 blocks

typedef __attribute__((ext_vector_type(8))) short s16x8;
typedef __attribute__((ext_vector_type(4))) float f32x4;
typedef __attribute__((ext_vector_type(4))) unsigned int u32x4;

__device__ __forceinline__ unsigned short f2bf(float f) {
  unsigned u = __builtin_bit_cast(unsigned, f);
  return (unsigned short)((u + 0x7FFFu + ((u >> 16) & 1u)) >> 16);  // RNE
}
// order-preserving map fp32 -> uint32 (no NaNs expected)
__device__ __forceinline__ unsigned fkey(float f) {
  unsigned u = __builtin_bit_cast(unsigned, f);
  return (u & 0x80000000u) ? ~u : (u | 0x80000000u);
}
// pack two fp32 to two bf16 (truncation) in one v_perm
__device__ __forceinline__ unsigned pk2(float hi, float lo) {
  return __builtin_amdgcn_perm(__builtin_bit_cast(unsigned, hi),
                               __builtin_bit_cast(unsigned, lo), 0x07060302u);
}

#define LDS_BARRIER()                                     \
  do {                                                    \
    asm volatile("s_waitcnt lgkmcnt(0)" ::: "memory");    \
    __builtin_amdgcn_s_barrier();                         \
  } while (0)

__device__ __forceinline__ float gelu_fast(float h) {
  const float t = 0.5f * h * h;
  const float u = 0.147f * t;
  const float num = t * (1.2732395f + u);
  const float den = 1.0f + u;
  const float r = num * __builtin_amdgcn_rcpf(den);
  const float e = __builtin_amdgcn_exp2f(r * -1.44269504f);
  const float s = __builtin_amdgcn_sqrtf(fmaxf(1.0f - e, 0.0f));
  const unsigned sgn = __builtin_bit_cast(unsigned, h) & 0x80000000u;
  const float erfv = __builtin_bit_cast(float, __builtin_bit_cast(unsigned, s) | sgn);
  return 0.5f * h * (1.0f + erfv);
}

// ---- w1 fp32 [C][H] -> plain bf16 transpose w1t[H][C] ----
__global__ void k_prep(const float* __restrict__ w1, unsigned short* __restrict__ w1t) {
  int i = blockIdx.x * blockDim.x + threadIdx.x;
  if (i < C_ * H_) {
    int c = i / H_, h = i % H_;
    w1t[h * C_ + c] = f2bf(w1[i]);
  }
}

// ---------------- fused scorer (round-16/19 structure — best measured) ----------------
__global__ __launch_bounds__(256) void k_score(
    const float* __restrict__ tokens, const unsigned short* __restrict__ w1t,
    const float* __restrict__ b1, const float* __restrict__ w2,
    const float* __restrict__ b2, float* __restrict__ scores_out) {
  __shared__ unsigned short lds_a[2][8 * 64 * 8];
  __shared__ float lds_c[4][16];

  const int tid = threadIdx.x;
  const int lane = tid & 63;
  const int l15 = lane & 15;
  const int l4 = lane >> 4;
  const int w = tid >> 6;

  s16x8 bfr0[8], bfr1[8];
  const int row0 = (2 * w) * 16 + l15;
  const int row1 = row0 + 16;
#pragma unroll
  for (int kk = 0; kk < 8; ++kk) {
    bfr0[kk] = *reinterpret_cast<const s16x8*>(w1t + row0 * 256 + (l4 + 4 * kk) * 8);
    bfr1[kk] = *reinterpret_cast<const s16x8*>(w1t + row1 * 256 + (l4 + 4 * kk) * 8);
  }
  const float b1v0 = b1[row0], b1v1 = b1[row1];
  const float w2v0 = w2[row0], w2v1 = w2[row1];
  const float b2v = b2[0];

  const int t = tid & 15;
  const int s = tid >> 4;
  const int g0 = blockIdx.x * GPB_;
  const float* tg = tokens + ((size_t)(g0 * 16 + t)) * 256 + s * 16;
  const int lb0 = (2 * s) * 128 + t * 8;
  const int lb1 = lb0 + 128;

  f32x4 vv[4];
  {
#pragma unroll
    for (int q = 0; q < 4; ++q) vv[q] = *reinterpret_cast<const f32x4*>(tg + 4 * q);
    u32x4 o0, o1;
    o0[0] = pk2(vv[0][1], vv[0][0]);
    o0[1] = pk2(vv[0][3], vv[0][2]);
    o0[2] = pk2(vv[1][1], vv[1][0]);
    o0[3] = pk2(vv[1][3], vv[1][2]);
    o1[0] = pk2(vv[2][1], vv[2][0]);
    o1[1] = pk2(vv[2][3], vv[2][2]);
    o1[2] = pk2(vv[3][1], vv[3][0]);
    o1[3] = pk2(vv[3][3], vv[3][2]);
    *reinterpret_cast<u32x4*>(&lds_a[0][lb0]) = o0;
    *reinterpret_cast<u32x4*>(&lds_a[0][lb1]) = o1;
  }
  LDS_BARRIER();

  int cur = 0;
  for (int i = 0; i < GPB_; ++i) {
    const int g = g0 + i;
    if (i + 1 < GPB_) {
      const float* p = tg + (size_t)(i + 1) * 4096;
#pragma unroll
      for (int q = 0; q < 4; ++q) vv[q] = *reinterpret_cast<const f32x4*>(p + 4 * q);
    }

    f32x4 acc0 = (f32x4){0.f, 0.f, 0.f, 0.f};
    f32x4 acc1 = (f32x4){0.f, 0.f, 0.f, 0.f};
#pragma unroll
    for (int kk = 0; kk < 8; ++kk) {
      s16x8 a = *reinterpret_cast<const s16x8*>(&lds_a[cur][(kk * 64 + lane) * 8]);
      acc0 = __builtin_amdgcn_mfma_f32_16x16x32_bf16(a, bfr0[kk], acc0, 0, 0, 0);
      acc1 = __builtin_amdgcn_mfma_f32_16x16x32_bf16(a, bfr1[kk], acc1, 0, 0, 0);
    }

    float p4[4];
#pragma unroll
    for (int rr = 0; rr < 4; ++rr) {
      float sp = gelu_fast(acc0[rr] + b1v0) * w2v0 + gelu_fast(acc1[rr] + b1v1) * w2v1;
      sp += __shfl_xor(sp, 1);
      sp += __shfl_xor(sp, 2);
      sp += __shfl_xor(sp, 4);
      sp += __shfl_xor(sp, 8);
      p4[rr] = sp;
    }
    if (l15 == 0) {
#pragma unroll
      for (int rr = 0; rr < 4; ++rr) lds_c[w][l4 * 4 + rr] = p4[rr];
    }
    LDS_BARRIER();  // (A)

    if (tid < 16) {
      scores_out[g * 16 + tid] =
          lds_c[0][tid] + lds_c[1][tid] + lds_c[2][tid] + lds_c[3][tid] + b2v;
    }
    if (i + 1 < GPB_) {
      u32x4 o0, o1;
      o0[0] = pk2(vv[0][1], vv[0][0]);
      o0[1] = pk2(vv[0][3], vv[0][2]);
      o0[2] = pk2(vv[1][1], vv[1][0]);
      o0[3] = pk2(vv[1][3], vv[1][2]);
      o1[0] = pk2(vv[2][1], vv[2][0]);
      o1[1] = pk2(vv[2][3], vv[2][2]);
      o1[2] = pk2(vv[3][1], vv[3][0]);
      o1[3] = pk2(vv[3][3], vv[3][2]);
      *reinterpret_cast<u32x4*>(&lds_a[cur ^ 1][lb0]) = o0;
      *reinterpret_cast<u32x4*>(&lds_a[cur ^ 1][lb1]) = o1;
    }
    LDS_BARRIER();  // (B)
    cur ^= 1;
  }
}

// ---- block exscan over 1024 threads; wave-parallel cross-wave scan ----
__device__ unsigned block_exscan_1024(unsigned v, volatile unsigned* wsum) {
  const int tid = threadIdx.x;
  const int lane = tid & 63;
  const int w = tid >> 6;  // 0..15
  unsigned x = v;
#pragma unroll
  for (int d = 1; d < 64; d <<= 1) {
    unsigned t = __shfl_up(x, d);
    if (lane >= d) x += t;
  }
  if (lane == 63) wsum[w] = x;
  __syncthreads();
  if (tid < 16) {
    unsigned s = wsum[tid];
#pragma unroll
    for (int d = 1; d < 16; d <<= 1) {
      unsigned u = __shfl_up(s, d);
      if (tid >= d) s += u;
    }
    wsum[tid] = s;  // inclusive wave sums
  }
  __syncthreads();
  unsigned r = (w ? wsum[w - 1] : 0u) + x - v;  // exclusive
  __syncthreads();  // protect wsum for the next call
  return r;
}

// ---------------- per-row top-K: 3-pass radix (11/11/10) + fused compaction ----------------
__global__ __launch_bounds__(1024) void k_select(const float* __restrict__ scores_f,
                                                 int* __restrict__ kept,
                                                 float* __restrict__ out_idx) {
  __shared__ unsigned hist[2048];   // 8 KB
  __shared__ unsigned wsum[16];
  __shared__ unsigned sh_T, sh_need;
  const int b = blockIdx.x;
  const int tid = threadIdx.x;
  const float* sp = scores_f + (size_t)b * N_;

  // ---- pass 0: bits [31:21] (11 bits, 2048 bins)
  hist[tid] = 0; hist[tid + 1024] = 0;
  __syncthreads();
  for (int i = tid; i < N_; i += 1024) atomicAdd(&hist[fkey(sp[i]) >> 21], 1u);
  __syncthreads();
  {
    const int hi = 2047 - 2 * tid, lo = hi - 1;
    const unsigned chi = hist[hi], pair = chi + hist[lo];
    unsigned before = block_exscan_1024(pair, wsum);  // keys in bins > hi
    if (before < K_ && before + chi >= K_) { sh_T = (unsigned)hi; sh_need = K_ - before; }
    else if (before + chi < K_ && before + pair >= K_) { sh_T = (unsigned)lo; sh_need = K_ - before - chi; }
  }
  __syncthreads();
  const unsigned T0 = sh_T;
  unsigned needK = sh_need;
  __syncthreads();

  // ---- pass 1: bits [20:10] among keys with top11 == T0
  hist[tid] = 0; hist[tid + 1024] = 0;
  __syncthreads();
  for (int i = tid; i < N_; i += 1024) {
    unsigned k = fkey(sp[i]);
    if ((k >> 21) == T0) atomicAdd(&hist[(k >> 10) & 2047u], 1u);
  }
  __syncthreads();
  {
    const int hi = 2047 - 2 * tid, lo = hi - 1;
    const unsigned chi = hist[hi], pair = chi + hist[lo];
    unsigned before = block_exscan_1024(pair, wsum);
    if (before < needK && before + chi >= needK) { sh_T = (unsigned)hi; sh_need = needK - before; }
    else if (before + chi < needK && before + pair >= needK) { sh_T = (unsigned)lo; sh_need = needK - before - chi; }
  }
  __syncthreads();
  const unsigned P21 = (T0 << 11) | sh_T;   // 21-bit prefix
  needK = sh_need;
  __syncthreads();

  // ---- pass 2: bits [9:0] among keys with top21 == P21 (1024 bins, 1/thread)
  hist[tid] = 0;
  __syncthreads();
  for (int i = tid; i < N_; i += 1024) {
    unsigned k = fkey(sp[i]);
    if ((k >> 10) == P21) atomicAdd(&hist[k & 1023u], 1u);
  }
  __syncthreads();
  {
    const int hi = 1023 - tid;
    const unsigned chi = hist[hi];
    unsigned before = block_exscan_1024(chi, wsum);
    if (before < needK && before + chi >= needK) { sh_T = (unsigned)hi; sh_need = needK - before; }
  }
  __syncthreads();
  const unsigned Tkey = (P21 << 10) | sh_T;   // exact K-th largest key
  const unsigned need = sh_need;              // #(==Tkey) kept, lowest index first
  __syncthreads();

  // ---- fused stable compaction: one packed exscan
  const int i0 = tid * 16;
  unsigned cgt = 0, ceq = 0;
  for (int j = 0; j < 16; ++j) {
    unsigned k = fkey(sp[i0 + j]);
    cgt += (k > Tkey);
    ceq += (k == Tkey);
  }
  unsigned packed = block_exscan_1024((cgt << 16) | ceq, wsum);
  unsigned gt_b = packed >> 16;
  unsigned eq_b = packed & 0xFFFFu;
  for (int j = 0; j < 16; ++j) {
    unsigned k = fkey(sp[i0 + j]);
    if (k > Tkey) {
      unsigned pos = gt_b + (eq_b < need ? eq_b : need);
      kept[(size_t)b * K_ + pos] = i0 + j;
      out_idx[(size_t)b * K_ + pos] = (float)(i0 + j);
      ++gt_b;
    } else if (k == Tkey) {
      if (eq_b < need) {
        unsigned pos = gt_b + eq_b;
        kept[(size_t)b * K_ + pos] = i0 + j;
        out_idx[(size_t)b * K_ + pos] = (float)(i0 + j);
      }
      ++eq_b;
    }
  }
}

// ---------------- gather kept token rows (fp32 -> fp32) ----------------
__global__ __launch_bounds__(256) void k_gather(const float* __restrict__ tokens,
                                                const int* __restrict__ kept,
                                                float* __restrict__ outp) {
  const int wid = (blockIdx.x * blockDim.x + threadIdx.x) >> 6;  // one wave per row
  const int lane = threadIdx.x & 63;
  if (wid >= B_ * K_) return;
  const int b = wid / K_;
  const int idx = kept[wid];
  const f32x4 v = *reinterpret_cast<const f32x4*>(tokens + ((size_t)b * N_ + idx) * C_ + lane * 4);
  *reinterpret_cast<f32x4*>(outp + (size_t)wid * C_ + lane * 4) = v;
}

extern "C" void kernel_launch(void* const* d_in, const int* in_sizes, int n_in,
                              void* d_out, int out_size, void* d_ws, size_t ws_size,
                              hipStream_t stream) {
  const float* tokens = (const float*)d_in[0];
  const float* w1 = (const float*)d_in[1];
  const float* b1 = (const float*)d_in[2];
  const float* w2 = (const float*)d_in[3];
  const float* b2 = (const float*)d_in[4];

  float* out = (float*)d_out;
  float* out_pruned = out;                                  // B*K*C fp32
  float* out_idx = out + (size_t)B_ * K_ * C_;              // B*K fp32
  float* out_scores = out_idx + (size_t)B_ * K_;            // B*N fp32

  char* ws = (char*)d_ws;
  unsigned short* w1t = (unsigned short*)ws;                // 64 KB plain bf16 W1^T
  int* kept = (int*)(ws + 0x10000);                         // B*K int32

  k_prep<<<dim3((C_ * H_ + 255) / 256), dim3(256), 0, stream>>>(w1, w1t);
  k_score<<<dim3(NBLK_), dim3(256), 0, stream>>>(tokens, w1t, b1, w2, b2, out_scores);
  k_select<<<dim3(B_), dim3(1024), 0, stream>>>(out_scores, kept, out_idx);
  k_gather<<<dim3((B_ * K_ + 3) / 4), dim3(256), 0, stream>>>(tokens, kept, out_pruned);
}